// Round 9
// baseline (2913.782 us; speedup 1.0000x reference)
//
#include <hip/hip_runtime.h>

#define NN 50000
#define NE 600000
#define FIN 128

// fp32 atomic add via integer CAS: safe on every memory type.
__device__ __forceinline__ void atomic_add_f32_cas(float* addr, float val) {
    unsigned int* ua = (unsigned int*)addr;
    union { float f; unsigned int u; } cur, nxt;
    unsigned int old = *ua;
    while (true) {
        cur.u = old;
        nxt.f = cur.f + val;
        unsigned int prev = atomicCAS(ua, old, nxt.u);
        if (prev == old) break;
        old = prev;
    }
}

// ---- graph preprocessing ---------------------------------------------------
__global__ void degree_kernel(const int* __restrict__ src, const int* __restrict__ dst,
                              int* __restrict__ deg_out, int* __restrict__ deg_in) {
    int e = blockIdx.x * 256 + threadIdx.x;
    if (e < NE) {
        atomicAdd(&deg_out[src[e]], 1);
        atomicAdd(&deg_in[dst[e]], 1);
    }
}

__global__ void norm_kernel(int* __restrict__ deg_out, int* __restrict__ deg_in) {
    int i = blockIdx.x * 256 + threadIdx.x;
    if (i < NN) {
        float a = (float)deg_out[i];
        float b = (float)deg_in[i];
        ((float*)deg_out)[i] = rsqrtf(fmaxf(a, 1.0f));  // norm_src
        ((float*)deg_in)[i]  = rsqrtf(fmaxf(b, 1.0f));  // norm_dst
    }
}

// agg[dst[e]] += x[src[e]] * norm_src[src[e]]  (x fp32; agg fp32 in d_out)
__global__ void scatter_kernel(const float* __restrict__ x,
                               const int* __restrict__ src, const int* __restrict__ dst,
                               const float* __restrict__ norm_src,
                               float* __restrict__ agg) {
    int gid = blockIdx.x * 256 + threadIdx.x;
    int e = gid >> 5;
    if (e >= NE) return;
    int c = (gid & 31) << 2;
    int s = src[e], d = dst[e];
    float ns = norm_src[s];
    float4 xv = *(const float4*)(x + (size_t)s * FIN + c);
    float* ap = agg + (size_t)d * FIN + c;
    atomic_add_f32_cas(ap + 0, xv.x * ns);
    atomic_add_f32_cas(ap + 1, xv.y * ns);
    atomic_add_f32_cas(ap + 2, xv.z * ns);
    atomic_add_f32_cas(ap + 3, xv.w * ns);
}

// ---- scalar fp32 GEMMs (one block per row; thread c computes column c) -----

// h1[r][c] = relu( sum_k (agg[r][k]*nd[r]) * W[k][c] + bias[c] ),  K=128
__global__ __launch_bounds__(256)
void gemm1_scalar(const float* __restrict__ agg, const float* __restrict__ norm_dst,
                  const float* __restrict__ W, const float* __restrict__ bias,
                  float* __restrict__ C, int ML) {
    __shared__ float ash[128];
    int r = blockIdx.x;
    if (r >= ML) return;
    int tid = threadIdx.x;
    float nd = norm_dst[r];
    if (tid < 128) ash[tid] = agg[(size_t)r * 128 + tid] * nd;
    __syncthreads();
    float acc = 0.0f;
    #pragma unroll 8
    for (int k = 0; k < 128; ++k)
        acc = fmaf(ash[k], W[(size_t)k * 256 + tid], acc);
    C[(size_t)r * 256 + tid] = fmaxf(acc + bias[tid], 0.0f);
}

// C[r][c] = act( sum_k A[r][k] * W[k][c] + bias[c] ),  K=256, all fp32
template<bool RELU>
__global__ __launch_bounds__(256)
void gemm23_scalar(const float* __restrict__ A,
                   const float* __restrict__ W, const float* __restrict__ bias,
                   float* __restrict__ C, int ML) {
    __shared__ float ash[256];
    int r = blockIdx.x;
    if (r >= ML) return;
    int tid = threadIdx.x;
    ash[tid] = A[(size_t)r * 256 + tid];
    __syncthreads();
    float acc = 0.0f;
    #pragma unroll 8
    for (int k = 0; k < 256; ++k)
        acc = fmaf(ash[k], W[(size_t)k * 256 + tid], acc);
    float v = acc + bias[tid];
    if (RELU) v = fmaxf(v, 0.0f);
    C[(size_t)r * 256 + tid] = v;
}

// ---- host-side orchestration ----------------------------------------------

extern "C" void kernel_launch(void* const* d_in, const int* in_sizes, int n_in,
                              void* d_out, int out_size, void* d_ws, size_t ws_size,
                              hipStream_t stream) {
    const float* x      = (const float*)d_in[0];
    const int*   src    = (const int*)d_in[1];
    const int*   dst    = (const int*)d_in[2];
    const float* W_conv = (const float*)d_in[3];
    const float* b_conv = (const float*)d_in[4];
    const float* W_fc   = (const float*)d_in[5];
    const float* b_fc   = (const float*)d_in[6];
    const float* W_fc2  = (const float*)d_in[7];
    const float* b_fc2  = (const float*)d_in[8];
    float* out = (float*)d_out;          // OUTPUT IS FP32 (reference dtype)

    // agg fp32[N,128] = 25.6MB lives in the lower half of d_out (51.2MB).
    // Final writes (out row r covers agg rows 2r,2r+1) destroy agg from
    // row 2*base upward -> process chunks in REVERSE base order so every
    // destroyed agg row belongs to an already-finished chunk.
    float* agg = (float*)d_out;

    // ws: [0,200000) deg_out/norm_src; [204800,404800) deg_in/norm_dst;
    //     [409728, 409728+2*CH*1024) h1/h2 fp32 chunk buffers
    //     (CH=12288 -> ends at 25.6MB, inside the proven-safe 26.3MB region)
    char* ws = (char*)d_ws;
    int*   deg_out_i = (int*)(ws + 0);
    int*   deg_in_i  = (int*)(ws + 204800);
    float* norm_src  = (float*)(ws + 0);
    float* norm_dst  = (float*)(ws + 204800);
    const int CH = 12288;
    float* h1 = (float*)(ws + 409728);
    float* h2 = h1 + (size_t)CH * 256;

    hipMemsetAsync(d_ws, 0, 409600, stream);                 // degrees
    hipMemsetAsync(d_out, 0, (size_t)NN * FIN * 4, stream);  // agg region

    degree_kernel<<<(NE + 255) / 256, 256, 0, stream>>>(src, dst, deg_out_i, deg_in_i);
    norm_kernel<<<(NN + 255) / 256, 256, 0, stream>>>(deg_out_i, deg_in_i);
    scatter_kernel<<<(NE * 32) / 256, 256, 0, stream>>>(x, src, dst, norm_src, agg);

    int nchunks = (NN + CH - 1) / CH;
    for (int ci = nchunks - 1; ci >= 0; --ci) {              // reverse order!
        int base = ci * CH;
        int ml = NN - base; if (ml > CH) ml = CH;
        gemm1_scalar<<<ml, 256, 0, stream>>>(agg + (size_t)base * FIN, norm_dst + base,
                                             W_conv, b_conv, h1, ml);
        gemm23_scalar<true ><<<ml, 256, 0, stream>>>(h1, W_fc,  b_fc,  h2, ml);
        gemm23_scalar<false><<<ml, 256, 0, stream>>>(h2, W_fc2, b_fc2,
                                                     out + (size_t)base * 256, ml);
    }
}

// Round 10
// 1252.861 us; speedup vs baseline: 2.3257x; 2.3257x over previous
//
#include <hip/hip_runtime.h>

#define NN 50000
#define NE 600000
#define FIN 128

typedef __attribute__((ext_vector_type(8))) short bf16x8;
typedef __attribute__((ext_vector_type(4))) float f32x4;

__device__ __forceinline__ float bf2f(unsigned short u) {
    union { unsigned int i; float f; } v; v.i = ((unsigned int)u) << 16; return v.f;
}
__device__ __forceinline__ unsigned short f2bf(float f) {
    union { float f; unsigned int i; } v; v.f = f;
    return (unsigned short)((v.i + 0x7FFFu + ((v.i >> 16) & 1u)) >> 16);
}

// ---- graph preprocessing ---------------------------------------------------
__global__ void degree_kernel(const int* __restrict__ src, const int* __restrict__ dst,
                              int* __restrict__ deg_out, int* __restrict__ deg_in) {
    int e = blockIdx.x * 256 + threadIdx.x;
    if (e < NE) {
        atomicAdd(&deg_out[src[e]], 1);
        atomicAdd(&deg_in[dst[e]], 1);
    }
}

__global__ void norm_kernel(int* __restrict__ deg_out, int* __restrict__ deg_in) {
    int i = blockIdx.x * 256 + threadIdx.x;
    if (i < NN) {
        float a = (float)deg_out[i];
        float b = (float)deg_in[i];
        ((float*)deg_out)[i] = rsqrtf(fmaxf(a, 1.0f));  // norm_src
        ((float*)deg_in)[i]  = rsqrtf(fmaxf(b, 1.0f));  // norm_dst
    }
}

// agg[dst[e]] += x[src[e]] * norm_src[src[e]]
// Native HW fp32 atomics (no CAS read-back): round 9's failure analysis
// exonerated them -- the rounds-2..4 bug was output dtype, not atomics.
__global__ void scatter_kernel(const float* __restrict__ x,
                               const int* __restrict__ src, const int* __restrict__ dst,
                               const float* __restrict__ norm_src,
                               float* __restrict__ agg) {
    int gid = blockIdx.x * 256 + threadIdx.x;
    int e = gid >> 5;
    if (e >= NE) return;
    int c = (gid & 31) << 2;
    int s = src[e], d = dst[e];
    float ns = norm_src[s];
    float4 xv = *(const float4*)(x + (size_t)s * FIN + c);
    float* ap = agg + (size_t)d * FIN + c;
    unsafeAtomicAdd(ap + 0, xv.x * ns);
    unsafeAtomicAdd(ap + 1, xv.y * ns);
    unsafeAtomicAdd(ap + 2, xv.z * ns);
    unsafeAtomicAdd(ap + 3, xv.w * ns);
}

// ---- MFMA GEMMs ------------------------------------------------------------
// mfma_f32_16x16x32_bf16 layouts (HW-verified, learn_hip m89/m91):
//   A[m][k]: m=lane&15, k=(lane>>4)*8+j   B[k][n]: n=lane&15, k=(lane>>4)*8+j
//   D: col=lane&15, row=(lane>>4)*4+reg
// Block = 4 waves, tile 64 rows x 64 cols; B tile staged fp32->bf16 in LDS
// (n-major, pitch K+24 shorts).

// GEMM1: h1 bf16[ML,256] = relu(bf16(agg[r]*nd[r]) @ W_conv + b1),  K=128
__global__ __launch_bounds__(256)
void gemm1_kernel(const float* __restrict__ agg, const float* __restrict__ norm_dst,
                  const float* __restrict__ W, const float* __restrict__ bias,
                  unsigned short* __restrict__ C, int ML) {
    const int K = 128, PITCH = K + 24;
    __shared__ short bsh[64 * PITCH];
    int tid  = threadIdx.x;
    int wave = tid >> 6, lane = tid & 63;
    int quad = lane >> 4, l16 = lane & 15;
    int n0 = blockIdx.y * 64;
    #pragma unroll
    for (int k0 = 0; k0 < K; k0 += 4) {
        int k = k0 + (tid >> 6);
        int c = tid & 63;
        bsh[c * PITCH + k] = (short)f2bf(W[(size_t)k * 256 + n0 + c]);
    }
    __syncthreads();

    int m0 = blockIdx.x * 64 + wave * 16;
    int arow = m0 + l16; if (arow >= ML) arow = ML - 1;
    float nd = norm_dst[arow];
    const float* Ap = agg + (size_t)arow * K + quad * 8;

    f32x4 acc0 = {0.f, 0.f, 0.f, 0.f};
    f32x4 acc1 = acc0, acc2 = acc0, acc3 = acc0;
    #pragma unroll
    for (int k0 = 0; k0 < K; k0 += 32) {
        float4 a0 = *(const float4*)(Ap + k0);
        float4 a1 = *(const float4*)(Ap + k0 + 4);
        bf16x8 a;
        a[0] = (short)f2bf(a0.x * nd); a[1] = (short)f2bf(a0.y * nd);
        a[2] = (short)f2bf(a0.z * nd); a[3] = (short)f2bf(a0.w * nd);
        a[4] = (short)f2bf(a1.x * nd); a[5] = (short)f2bf(a1.y * nd);
        a[6] = (short)f2bf(a1.z * nd); a[7] = (short)f2bf(a1.w * nd);
        bf16x8 b0 = *(const bf16x8*)&bsh[( 0 + l16) * PITCH + quad * 8 + k0];
        bf16x8 b1 = *(const bf16x8*)&bsh[(16 + l16) * PITCH + quad * 8 + k0];
        bf16x8 b2 = *(const bf16x8*)&bsh[(32 + l16) * PITCH + quad * 8 + k0];
        bf16x8 b3 = *(const bf16x8*)&bsh[(48 + l16) * PITCH + quad * 8 + k0];
        acc0 = __builtin_amdgcn_mfma_f32_16x16x32_bf16(a, b0, acc0, 0, 0, 0);
        acc1 = __builtin_amdgcn_mfma_f32_16x16x32_bf16(a, b1, acc1, 0, 0, 0);
        acc2 = __builtin_amdgcn_mfma_f32_16x16x32_bf16(a, b2, acc2, 0, 0, 0);
        acc3 = __builtin_amdgcn_mfma_f32_16x16x32_bf16(a, b3, acc3, 0, 0, 0);
    }
    f32x4 accs[4] = {acc0, acc1, acc2, acc3};
    #pragma unroll
    for (int c = 0; c < 4; ++c) {
        int col = n0 + c * 16 + l16;
        float bv = bias[col];
        #pragma unroll
        for (int r = 0; r < 4; ++r) {
            int rr = m0 + quad * 4 + r;
            if (rr < ML)
                C[(size_t)rr * 256 + col] = f2bf(fmaxf(accs[c][r] + bv, 0.0f));
        }
    }
}

// GEMM2/3: K=256, A bf16[ML,256]; RELU -> bf16 h2, else fp32 final out.
template<bool RELU>
__global__ __launch_bounds__(256)
void gemm_kernel(const unsigned short* __restrict__ A,
                 const float* __restrict__ W, const float* __restrict__ bias,
                 unsigned short* __restrict__ Cb, float* __restrict__ Cf, int ML) {
    const int K = 256, PITCH = K + 24;
    __shared__ short bsh[64 * PITCH];
    int tid  = threadIdx.x;
    int wave = tid >> 6, lane = tid & 63;
    int quad = lane >> 4, l16 = lane & 15;
    int n0 = blockIdx.y * 64;
    #pragma unroll
    for (int k0 = 0; k0 < K; k0 += 4) {
        int k = k0 + (tid >> 6);
        int c = tid & 63;
        bsh[c * PITCH + k] = (short)f2bf(W[(size_t)k * 256 + n0 + c]);
    }
    __syncthreads();

    int m0 = blockIdx.x * 64 + wave * 16;
    int arow = m0 + l16; if (arow >= ML) arow = ML - 1;
    const unsigned short* Ap = A + (size_t)arow * K + quad * 8;

    f32x4 acc0 = {0.f, 0.f, 0.f, 0.f};
    f32x4 acc1 = acc0, acc2 = acc0, acc3 = acc0;
    #pragma unroll
    for (int k0 = 0; k0 < K; k0 += 32) {
        bf16x8 a  = *(const bf16x8*)(Ap + k0);
        bf16x8 b0 = *(const bf16x8*)&bsh[( 0 + l16) * PITCH + quad * 8 + k0];
        bf16x8 b1 = *(const bf16x8*)&bsh[(16 + l16) * PITCH + quad * 8 + k0];
        bf16x8 b2 = *(const bf16x8*)&bsh[(32 + l16) * PITCH + quad * 8 + k0];
        bf16x8 b3 = *(const bf16x8*)&bsh[(48 + l16) * PITCH + quad * 8 + k0];
        acc0 = __builtin_amdgcn_mfma_f32_16x16x32_bf16(a, b0, acc0, 0, 0, 0);
        acc1 = __builtin_amdgcn_mfma_f32_16x16x32_bf16(a, b1, acc1, 0, 0, 0);
        acc2 = __builtin_amdgcn_mfma_f32_16x16x32_bf16(a, b2, acc2, 0, 0, 0);
        acc3 = __builtin_amdgcn_mfma_f32_16x16x32_bf16(a, b3, acc3, 0, 0, 0);
    }
    f32x4 accs[4] = {acc0, acc1, acc2, acc3};
    #pragma unroll
    for (int c = 0; c < 4; ++c) {
        int col = n0 + c * 16 + l16;
        float bv = bias[col];
        #pragma unroll
        for (int r = 0; r < 4; ++r) {
            int rr = m0 + quad * 4 + r;
            if (rr < ML) {
                float v = accs[c][r] + bv;
                if (RELU) Cb[(size_t)rr * 256 + col] = f2bf(fmaxf(v, 0.0f));
                else      Cf[(size_t)rr * 256 + col] = v;
            }
        }
    }
}

// ---- host-side orchestration ----------------------------------------------

extern "C" void kernel_launch(void* const* d_in, const int* in_sizes, int n_in,
                              void* d_out, int out_size, void* d_ws, size_t ws_size,
                              hipStream_t stream) {
    const float* x      = (const float*)d_in[0];
    const int*   src    = (const int*)d_in[1];
    const int*   dst    = (const int*)d_in[2];
    const float* W_conv = (const float*)d_in[3];
    const float* b_conv = (const float*)d_in[4];
    const float* W_fc   = (const float*)d_in[5];
    const float* b_fc   = (const float*)d_in[6];
    const float* W_fc2  = (const float*)d_in[7];
    const float* b_fc2  = (const float*)d_in[8];
    float* out = (float*)d_out;          // fp32 output (reference dtype)

    // agg fp32[N,128] = 25.6MB in d_out's lower half (out is 51.2MB).
    // Chunks processed in REVERSE row order: chunk at base destroys only
    // agg rows >= 2*base, all consumed by already-finished chunks (round-9
    // validated).
    float* agg = (float*)d_out;

    // ws: [0,200000) deg_out/norm_src; [204800,404800) deg_in/norm_dst;
    //     [409728, +CH*1024) h1/h2 bf16 chunk buffers (512 B per row each)
    char* ws = (char*)d_ws;
    int*   deg_out_i = (int*)(ws + 0);
    int*   deg_in_i  = (int*)(ws + 204800);
    float* norm_src  = (float*)(ws + 0);
    float* norm_dst  = (float*)(ws + 204800);

    size_t avail = (ws_size > 409728) ? ws_size - 409728 : 0;
    long long cap = (long long)(avail / 1024);          // rows for h1+h2 pair
    int CH = (int)((cap / 64) * 64);
    if (CH < 64) CH = 64;
    if (CH > 50048) CH = 50048;
    unsigned short* h1 = (unsigned short*)(ws + 409728);
    unsigned short* h2 = h1 + (size_t)CH * 256;

    hipMemsetAsync(d_ws, 0, 409600, stream);                 // degrees
    hipMemsetAsync(d_out, 0, (size_t)NN * FIN * 4, stream);  // agg region

    degree_kernel<<<(NE + 255) / 256, 256, 0, stream>>>(src, dst, deg_out_i, deg_in_i);
    norm_kernel<<<(NN + 255) / 256, 256, 0, stream>>>(deg_out_i, deg_in_i);
    scatter_kernel<<<(NE * 32) / 256, 256, 0, stream>>>(x, src, dst, norm_src, agg);

    int nchunks = (NN + CH - 1) / CH;
    for (int ci = nchunks - 1; ci >= 0; --ci) {              // reverse order!
        int base = ci * CH;
        int ml = NN - base; if (ml > CH) ml = CH;
        dim3 g((ml + 63) / 64, 4);
        gemm1_kernel<<<g, 256, 0, stream>>>(agg + (size_t)base * FIN, norm_dst + base,
                                            W_conv, b_conv, h1, ml);
        gemm_kernel<true ><<<g, 256, 0, stream>>>(h1, W_fc,  b_fc,  h2, nullptr, ml);
        gemm_kernel<false><<<g, 256, 0, stream>>>(h2, W_fc2, b_fc2, nullptr,
                                                  out + (size_t)base * 256, ml);
    }
}